// Round 2
// baseline (253.849 us; speedup 1.0000x reference)
//
#include <hip/hip_runtime.h>
#include <hip/hip_bf16.h>

#define CHAR_EMB 30
#define NFILT    30
#define WLEN     40
#define TOUT     38      // WLEN - K + 1
#define OUTC     900     // CHAR_EMB * NFILT
#define WORD_EMB 100
#define RP2      42      // LDS row stride in float2 (42*8=336 B, 16B aligned)

__device__ __forceinline__ float2 f2fma(float w, float2 a, float2 c) {
    return make_float2(fmaf(w, a.x, c.x), fmaf(w, a.y, c.y));
}
__device__ __forceinline__ float2 f2mul(float w, float2 a) {
    return make_float2(w * a.x, w * a.y);
}
__device__ __forceinline__ float2 f2max(float2 a, float2 b) {
    return make_float2(fmaxf(a.x, b.x), fmaxf(a.y, b.y));
}

// One block processes TWO words (x-lanes packed in float2).
// Threads 0..299: 3 consecutive output channels each (all in one group ->
// one LDS row load serves 3 filters x 2 words).
__global__ __launch_bounds__(320) void encoder_kernel(
    const int*   __restrict__ char_ids,   // [BS, 40]
    const int*   __restrict__ word_ids,   // [BS]
    const float* __restrict__ char_emb,   // [102, 30]
    const float* __restrict__ conv_w,     // [900, 1, 3]
    const float* __restrict__ conv_b,     // [900]
    const float* __restrict__ glove,      // [400002, 100]
    float*       __restrict__ out,        // [BS, 1000]
    int BS)
{
    const int nA  = 2 * blockIdx.x;
    const int nB  = nA + 1;
    const bool hasB = (nB < BS);
    const int tid = threadIdx.x;

    __shared__ __align__(16) float2 xs[CHAR_EMB * RP2]; // xs[c*RP2+t] = {xA[c][t], xB[c][t]}
    __shared__ int cidA[WLEN];
    __shared__ int cidB[WLEN];

    if (tid < WLEN)                    cidA[tid]        = char_ids[nA * WLEN + tid];
    else if (tid < 2 * WLEN && hasB)   cidB[tid - WLEN] = char_ids[nB * WLEN + (tid - WLEN)];
    else if (tid < 2 * WLEN)           cidB[tid - WLEN] = 0;
    __syncthreads();

    // gather char embeddings for both words: 1200 (t,c) pairs
    for (int i = tid; i < WLEN * CHAR_EMB; i += 320) {
        const int t = i / CHAR_EMB;
        const int c = i - t * CHAR_EMB;
        const float a = char_emb[cidA[t] * CHAR_EMB + c];
        const float b = char_emb[cidB[t] * CHAR_EMB + c];
        xs[c * RP2 + t] = make_float2(a, b);
    }
    __syncthreads();

    float* orowA = out + (long)nA * (OUTC + WORD_EMB);
    float* orowB = out + (long)nB * (OUTC + WORD_EMB);

    if (tid < 300) {
        const int o0 = 3 * tid;        // 3 consecutive channels, same group
        const int g  = tid / 10;       // o0/30

        // load the 40-element float2 row once: 20 x b128
        float2 xr[WLEN];
        const float4* rp = reinterpret_cast<const float4*>(&xs[g * RP2]);
        #pragma unroll
        for (int k = 0; k < WLEN / 2; ++k) {
            float4 q = rp[k];
            xr[2 * k + 0] = make_float2(q.x, q.y);
            xr[2 * k + 1] = make_float2(q.z, q.w);
        }

        // 9 consecutive weights
        float w[9];
        #pragma unroll
        for (int j = 0; j < 9; ++j) w[j] = conv_w[9 * tid + j];

        #pragma unroll
        for (int f = 0; f < 3; ++f) {
            const float w0 = w[3 * f + 0], w1 = w[3 * f + 1], w2 = w[3 * f + 2];
            float2 m2 = make_float2(-3.4e38f, -3.4e38f);
            #pragma unroll
            for (int t = 0; t < TOUT; ++t) {
                float2 v = f2fma(w0, xr[t], f2fma(w1, xr[t + 1], f2mul(w2, xr[t + 2])));
                m2 = f2max(m2, v);
            }
            const float b = conv_b[o0 + f];
            orowA[o0 + f] = m2.x + b;
            if (hasB) orowB[o0 + f] = m2.y + b;
        }
    }

    // glove copy: threads 0..99 word A, 100..199 word B
    if (tid < WORD_EMB) {
        const int wid = word_ids[nA];
        orowA[OUTC + tid] = glove[(long)wid * WORD_EMB + tid];
    } else if (tid < 2 * WORD_EMB && hasB) {
        const int j = tid - WORD_EMB;
        const int wid = word_ids[nB];
        orowB[OUTC + j] = glove[(long)wid * WORD_EMB + j];
    }
}

extern "C" void kernel_launch(void* const* d_in, const int* in_sizes, int n_in,
                              void* d_out, int out_size, void* d_ws, size_t ws_size,
                              hipStream_t stream) {
    const int*   char_ids = (const int*)  d_in[0];
    const int*   word_ids = (const int*)  d_in[1];
    const float* char_emb = (const float*)d_in[2];
    const float* conv_w   = (const float*)d_in[3];
    const float* conv_b   = (const float*)d_in[4];
    const float* glove    = (const float*)d_in[5];
    float*       out      = (float*)      d_out;

    const int BS = in_sizes[1];          // 8192 words
    const int nblk = (BS + 1) / 2;

    encoder_kernel<<<nblk, 320, 0, stream>>>(
        char_ids, word_ids, char_emb, conv_w, conv_b, glove, out, BS);
}

// Round 3
// 234.896 us; speedup vs baseline: 1.0807x; 1.0807x over previous
//
#include <hip/hip_runtime.h>
#include <hip/hip_bf16.h>

#define CHAR_EMB 30
#define NFILT    30
#define WLEN     40
#define TOUT     38      // WLEN - K + 1
#define OUTC     900     // CHAR_EMB * NFILT
#define WORD_EMB 100
#define RP2      42      // LDS row stride in float2 (42*8 = 336 B, 16B aligned)

// elementwise float2 helpers written so SLP vectorizer forms <2 x float>
// fma/mul -> v_pk_fma_f32 / v_pk_mul_f32 (packed fp32, double-rate on CDNA)
__device__ __forceinline__ float2 F2FMA(float2 w, float2 a, float2 c) {
    return make_float2(fmaf(w.x, a.x, c.x), fmaf(w.y, a.y, c.y));
}
__device__ __forceinline__ float2 F2MUL(float2 w, float2 a) {
    return make_float2(w.x * a.x, w.y * a.y);
}

// One block = TWO consecutive words packed in float2 lanes.
// Threads 0..239: group g = tid/8, filters f = (tid%8) + {0,8,16,24} < 30.
// One 40-float2 row load (20 x ds_read_b128) serves up to 4 filters x 2 words.
__global__ __launch_bounds__(256) void encoder_kernel(
    const int*   __restrict__ char_ids,   // [BS, 40]
    const int*   __restrict__ word_ids,   // [BS]
    const float* __restrict__ char_emb,   // [102, 30]
    const float* __restrict__ conv_w,     // [900, 1, 3]
    const float* __restrict__ conv_b,     // [900]
    const float* __restrict__ glove,      // [400002, 100]
    float*       __restrict__ out,        // [BS, 1000]
    int BS)
{
    const int nA   = 2 * blockIdx.x;
    const int nB   = nA + 1;
    const bool hasB = (nB < BS);
    const int tid  = threadIdx.x;

    __shared__ int cid[2 * WLEN];
    __shared__ __align__(16) float2 xs[CHAR_EMB * RP2];  // xs[c*RP2+t] = {xA[c][t], xB[c][t]}

    float* orowA = out + (long)nA * (OUTC + WORD_EMB);
    float* orowB = out + (long)nB * (OUTC + WORD_EMB);

    // glove copy first (pure global->global, no LDS dependency): float4 x 25
    if (tid < 25) {
        const float4* gp = reinterpret_cast<const float4*>(glove + (long)word_ids[nA] * WORD_EMB);
        reinterpret_cast<float4*>(orowA + OUTC)[tid] = gp[tid];
    } else if (tid < 50 && hasB) {
        const int j = tid - 25;
        const float4* gp = reinterpret_cast<const float4*>(glove + (long)word_ids[nB] * WORD_EMB);
        reinterpret_cast<float4*>(orowB + OUTC)[j] = gp[j];
    }

    // stage char ids: rows nA,nB are contiguous (80 consecutive ints)
    if (tid < 2 * WLEN) {
        cid[tid] = (tid < WLEN || hasB) ? char_ids[nA * WLEN + tid] : 0;
    }
    __syncthreads();

    // gather char embeddings for both words: 1200 (t,c) pairs -> float2 LDS
    for (int i = tid; i < WLEN * CHAR_EMB; i += 256) {
        const int t = i / CHAR_EMB;
        const int c = i - t * CHAR_EMB;
        const float a = char_emb[cid[t] * CHAR_EMB + c];
        const float b = char_emb[cid[WLEN + t] * CHAR_EMB + c];
        xs[c * RP2 + t] = make_float2(a, b);
    }
    __syncthreads();

    if (tid < 240) {
        const int g = tid >> 3;        // group 0..29
        const int j = tid & 7;         // filter phase 0..7

        // load the group's 40-position float2 row once: 20 x b128
        float2 xr[WLEN];
        const float4* rp = reinterpret_cast<const float4*>(&xs[g * RP2]);
        #pragma unroll
        for (int k = 0; k < WLEN / 2; ++k) {
            float4 q = rp[k];
            xr[2 * k + 0] = make_float2(q.x, q.y);
            xr[2 * k + 1] = make_float2(q.z, q.w);
        }

        #pragma unroll
        for (int f = j; f < NFILT; f += 8) {
            const int o = g * NFILT + f;
            const float w0 = conv_w[o * 3 + 0];
            const float w1 = conv_w[o * 3 + 1];
            const float w2 = conv_w[o * 3 + 2];
            const float2 W0 = make_float2(w0, w0);
            const float2 W1 = make_float2(w1, w1);
            const float2 W2 = make_float2(w2, w2);

            float mA = -3.4e38f, mB = -3.4e38f;
            #pragma unroll
            for (int i = 0; i < TOUT / 2; ++i) {
                const int t = 2 * i;
                float2 v0 = F2FMA(W0, xr[t],     F2FMA(W1, xr[t + 1], F2MUL(W2, xr[t + 2])));
                float2 v1 = F2FMA(W0, xr[t + 1], F2FMA(W1, xr[t + 2], F2MUL(W2, xr[t + 3])));
                mA = fmaxf(fmaxf(mA, v0.x), v1.x);   // -> v_max3_f32
                mB = fmaxf(fmaxf(mB, v0.y), v1.y);
            }
            const float b = conv_b[o];
            orowA[o] = mA + b;
            if (hasB) orowB[o] = mB + b;
        }
    }
}

extern "C" void kernel_launch(void* const* d_in, const int* in_sizes, int n_in,
                              void* d_out, int out_size, void* d_ws, size_t ws_size,
                              hipStream_t stream) {
    const int*   char_ids = (const int*)  d_in[0];
    const int*   word_ids = (const int*)  d_in[1];
    const float* char_emb = (const float*)d_in[2];
    const float* conv_w   = (const float*)d_in[3];
    const float* conv_b   = (const float*)d_in[4];
    const float* glove    = (const float*)d_in[5];
    float*       out      = (float*)      d_out;

    const int BS = in_sizes[1];          // 8192 words
    const int nblk = (BS + 1) / 2;

    encoder_kernel<<<nblk, 256, 0, stream>>>(
        char_ids, word_ids, char_emb, conv_w, conv_b, glove, out, BS);
}